// Round 18
// baseline (168.803 us; speedup 1.0000x reference)
//
#include <hip/hip_runtime.h>

#define NGRP 512        // dst-range groups; requires n <= 131072 (SRC_BITS) and GN <= 512
#define CAP  7424       // per-group capacity incl. padding (raw ~6250+5sigma, +3*GN pad)
#define PTHREADS 1024   // partition block threads
#define NE   16         // edges register-cached per thread
#define EPB  (PTHREADS * NE)   // 16384 edges per partition block
#define NREP 4          // LDS bin replicas (contention /4)
#define SRC_BITS 17
#define SRC_MASK 0x1FFFF

// ---- bf16 helpers (manual, RNE) ----
static __device__ __forceinline__ unsigned f2bf(float f) {
    unsigned u = __float_as_uint(f);
    return (u + 0x7FFFu + ((u >> 16) & 1u)) >> 16;
}
static __device__ __forceinline__ float bf2f_lo(unsigned u) { return __uint_as_float(u << 16); }
static __device__ __forceinline__ float bf2f_hi(unsigned u) { return __uint_as_float(u & 0xFFFF0000u); }

// ---------------- CSR build ----------------

// single global read of ei; 4-way replicated LDS bins to cut atomic contention.
// gcursor[] zeroed by hipMemsetAsync; holds per-group RELATIVE counts.
__global__ __launch_bounds__(PTHREADS) void k_partition(const int* __restrict__ ei, int* gcursor,
                                                        unsigned* __restrict__ pairs,
                                                        int E, int n, int GN) {
    __shared__ int cnt[NGRP][NREP];
    __shared__ int cur[NGRP][NREP];
    int tid = threadIdx.x;
    int r = tid & (NREP - 1);
    for (int k = tid; k < NGRP * NREP; k += PTHREADS) ((int*)cnt)[k] = 0;
    __syncthreads();
    int base = blockIdx.x * EPB;
    int sreg[NE], dreg[NE];
#pragma unroll
    for (int k = 0; k < NE; ++k) {
        int e = base + tid + k * PTHREADS;    // coalesced
        int d = -1, s = 0;
        if (e < E) {
            s = ei[e];
            d = ei[E + e];
            if ((unsigned)s < (unsigned)n && (unsigned)d < (unsigned)n)
                atomicAdd(&cnt[d / GN][r], 1);
            else d = -1;
        }
        sreg[k] = s; dreg[k] = d;
    }
    __syncthreads();
    if (tid < NGRP) {
        int c0 = cnt[tid][0], c1 = cnt[tid][1], c2 = cnt[tid][2], c3 = cnt[tid][3];
        int tot = c0 + c1 + c2 + c3;
        int rel = tot ? atomicAdd(&gcursor[tid], tot) : 0;
        int b0 = tid * CAP + rel;             // absolute; replicas get disjoint sub-ranges
        cur[tid][0] = b0;
        cur[tid][1] = b0 + c0;
        cur[tid][2] = b0 + c0 + c1;
        cur[tid][3] = b0 + c0 + c1 + c2;
    }
    __syncthreads();
#pragma unroll
    for (int k = 0; k < NE; ++k) {
        int d = dreg[k];
        if (d >= 0) {
            int g = d / GN;
            int w = atomicAdd(&cur[g][r], 1);
            if (w < (g + 1) * CAP)   // capacity guard: drop -> loud absmax fail, no corruption
                pairs[w] = ((unsigned)(d - g * GN) << SRC_BITS) | (unsigned)sreg[k];
        }
    }
}

// one 512-thread block per group: LDS-stage pairs, hist, PADDED scan (each node's list
// rounded to multiple of 4; pad entries -> zero-row n), rowStart/rowEnd/dinv/z, scatter.
__global__ __launch_bounds__(512) void k_build(const int* __restrict__ gcursor,
                                               const unsigned* __restrict__ pairs,
                                               const float2* __restrict__ x2,
                                               int* __restrict__ rowStart, int* __restrict__ rowEnd,
                                               int* __restrict__ srclist, float* __restrict__ dinv,
                                               float2* __restrict__ z, int n, int GN) {
    __shared__ unsigned pl[CAP];
    __shared__ int cnt[512];
    __shared__ int cur[512];
    int g = blockIdx.x;
    int t = threadIdx.x;
    int gbeg = g * CAP;
    int m = gcursor[g];                 // raw count
    const int MCAP = CAP - 600;         // leave room for padding (<= 3*GN = 588)
    if (m > MCAP) m = MCAP;             // pathological overflow -> drop (loud fail)
    cnt[t] = 0;
    if (g == 0 && t == 0) z[n] = make_float2(0.f, 0.f);   // zero row for padding
    __syncthreads();
    for (int k = t; k < m; k += 512) {
        unsigned v = pairs[gbeg + k];
        pl[k] = v;
        atomicAdd(&cnt[(v >> SRC_BITS) & 511], 1);
    }
    __syncthreads();
    int c = cnt[t];
    int rnd = (c + 3) & ~3;             // padded length (multiple of 4)
    __syncthreads();
    cnt[t] = rnd;
    __syncthreads();
    for (int off = 1; off < 512; off <<= 1) {   // inclusive scan of padded lengths
        int add = (t >= off) ? cnt[t - off] : 0;
        __syncthreads();
        cnt[t] += add;
        __syncthreads();
    }
    int excl = cnt[t] - rnd;
    int node = g * GN + t;
    int st = gbeg + excl;
    if (t < GN && node < n) {
        rowStart[node] = st;
        rowEnd[node] = st + rnd;
        float di = rsqrtf(1.0f + (float)c);
        dinv[node] = di;
        float2 xv = x2[node];
        z[node] = make_float2(xv.x * di, xv.y * di);
        for (int j = c; j < rnd; ++j) srclist[st + j] = n;   // padding -> zero row
    }
    cur[t] = excl;
    __syncthreads();
    for (int k = t; k < m; k += 512) {
        unsigned v = pl[k];
        int dl = (v >> SRC_BITS) & 511;
        int pos = atomicAdd(&cur[dl], 1);
        srclist[gbeg + pos] = (int)(v & SRC_MASK);
    }
}

// ---------------- GCN compute ----------------

// conv1 aggregation, ONE lane per node, int4 srclist, 4 independent z loads per iter.
// z is 800KB -> L2-resident. agg[i] = z[i] + sum_{s->i} z[s] (padding hits z[n]=0).
__global__ __launch_bounds__(256) void k_gather2f(const int* __restrict__ rowStart,
                                                  const int* __restrict__ rowEnd,
                                                  const int* __restrict__ srclist,
                                                  const float2* __restrict__ z,
                                                  float2* __restrict__ agg, int n) {
    int w = blockIdx.x * 256 + threadIdx.x;
    if (w >= n) return;
    int beg = rowStart[w];
    int nq = (rowEnd[w] - beg) >> 2;
    const int4* sl4 = (const int4*)(srclist + beg);
    float ax = 0.f, ay = 0.f;
    for (int j = 0; j < nq; ++j) {
        int4 s4 = sl4[j];
        float2 v0 = z[s4.x], v1 = z[s4.y], v2 = z[s4.z], v3 = z[s4.w];
        ax += v0.x + v1.x + v2.x + v3.x;
        ay += v0.y + v1.y + v2.y + v3.y;
    }
    float2 zz = z[w];   // self-loop
    agg[w] = make_float2(ax + zz.x, ay + zz.y);
}

// h1 = relu(dinv*(agg@W1) + b1); y = bf16((h1 @ W2) * dinv) into two feature planes.
// Grid covers i==n to zero the y planes' padding row.
__global__ void k_mid1(const float2* __restrict__ agg, const float* __restrict__ dinv,
                       const float* __restrict__ W1, const float* __restrict__ b1,
                       const float* __restrict__ W2, unsigned short* __restrict__ y0,
                       unsigned short* __restrict__ y1, int n) {
    __shared__ float sW[1024];
    __shared__ float sh[8][33];
    int tid = threadIdx.x;
    for (int k = tid; k < 1024; k += 256) sW[k] = W2[k];
    int ln = tid >> 5, f = tid & 31;
    int i = blockIdx.x * 8 + ln;
    float h = 0.f, di = 0.f;
    if (i < n) {
        di = dinv[i];
        float2 a = agg[i];
        h = di * (a.x * W1[f] + a.y * W1[32 + f]) + b1[f];
        h = h > 0.f ? h : 0.f;
    }
    sh[ln][f] = h;
    __syncthreads();
    if (i < n) {
        float acc = 0.f;
#pragma unroll
        for (int k = 0; k < 32; ++k) acc += sh[ln][k] * sW[k * 32 + f];
        unsigned short* ypl = (f < 16) ? y0 : y1;
        ypl[(size_t)i * 16 + (f & 15)] = (unsigned short)f2bf(acc * di);
    } else if (i == n) {
        unsigned short* ypl = (f < 16) ? y0 : y1;   // zero row for conv2 padding
        ypl[(size_t)n * 16 + (f & 15)] = 0;
    }
}

#define ACC8(v)                                        \
    a0 += bf2f_lo((v).x); a1 += bf2f_hi((v).x);        \
    a2 += bf2f_lo((v).y); a3 += bf2f_hi((v).y);        \
    a4 += bf2f_lo((v).z); a5 += bf2f_hi((v).z);        \
    a6 += bf2f_lo((v).w); a7 += bf2f_hi((v).w);

// conv2 gather + fused epilogue: h2 = relu(dinv*sum + b2) written as bf16 planes.
// XCD-sharded planes (supergroups of 8 blocks). int4 srclist loads (rows padded to 4).
__global__ __launch_bounds__(256) void k_gather_planes(const int* __restrict__ rowStart,
                                                       const int* __restrict__ rowEnd,
                                                       const int* __restrict__ srclist,
                                                       const uint4* __restrict__ yp0,
                                                       const uint4* __restrict__ yp1,
                                                       const float* __restrict__ dinv,
                                                       const float* __restrict__ b2,
                                                       unsigned short* __restrict__ h2_0,
                                                       unsigned short* __restrict__ h2_1,
                                                       int n, int nb) {
    int blk = blockIdx.x;
    int p = (blk >> 2) & 1;                      // plane by XCD half
    int b = (blk >> 3) * 4 + (blk & 3);          // node-block index
    if (b >= nb) return;
    const uint4* yh = p ? yp1 : yp0;
    unsigned short* hp = p ? h2_1 : h2_0;
    int w = b * 64 + (threadIdx.x >> 2);
    if (w >= n) return;
    int slot = (threadIdx.x >> 1) & 1;
    int q = threadIdx.x & 1;
    int beg = rowStart[w];
    int nq = (rowEnd[w] - beg) >> 2;             // int4 quads (padding -> zero rows)
    const int4* sl4 = (const int4*)(srclist + beg);
    float a0 = 0.f, a1 = 0.f, a2 = 0.f, a3 = 0.f, a4 = 0.f, a5 = 0.f, a6 = 0.f, a7 = 0.f;
    for (int j = slot; j < nq; j += 2) {
        int4 s4 = sl4[j];
        uint4 v0 = yh[(size_t)s4.x * 2 + q];
        uint4 v1 = yh[(size_t)s4.y * 2 + q];
        uint4 v2 = yh[(size_t)s4.z * 2 + q];
        uint4 v3 = yh[(size_t)s4.w * 2 + q];
        ACC8(v0); ACC8(v1); ACC8(v2); ACC8(v3);
    }
    if (slot == 0) {                     // self-loop
        uint4 v = yh[(size_t)w * 2 + q];
        ACC8(v);
    }
    a0 += __shfl_xor(a0, 2, 64);
    a1 += __shfl_xor(a1, 2, 64);
    a2 += __shfl_xor(a2, 2, 64);
    a3 += __shfl_xor(a3, 2, 64);
    a4 += __shfl_xor(a4, 2, 64);
    a5 += __shfl_xor(a5, 2, 64);
    a6 += __shfl_xor(a6, 2, 64);
    a7 += __shfl_xor(a7, 2, 64);
    if (slot == 0) {
        float di = dinv[w];
        const float* bb = b2 + p * 16 + q * 8;
        float t0 = di * a0 + bb[0]; t0 = t0 > 0.f ? t0 : 0.f;
        float t1 = di * a1 + bb[1]; t1 = t1 > 0.f ? t1 : 0.f;
        float t2 = di * a2 + bb[2]; t2 = t2 > 0.f ? t2 : 0.f;
        float t3 = di * a3 + bb[3]; t3 = t3 > 0.f ? t3 : 0.f;
        float t4 = di * a4 + bb[4]; t4 = t4 > 0.f ? t4 : 0.f;
        float t5 = di * a5 + bb[5]; t5 = t5 > 0.f ? t5 : 0.f;
        float t6 = di * a6 + bb[6]; t6 = t6 > 0.f ? t6 : 0.f;
        float t7 = di * a7 + bb[7]; t7 = t7 > 0.f ? t7 : 0.f;
        uint4 pk;
        pk.x = f2bf(t0) | (f2bf(t1) << 16);
        pk.y = f2bf(t2) | (f2bf(t3) << 16);
        pk.z = f2bf(t4) | (f2bf(t5) << 16);
        pk.w = f2bf(t6) | (f2bf(t7) << 16);
        *(uint4*)(hp + (size_t)w * 16 + q * 8) = pk;
    }
}

// h3 = relu(h2 @ Wf1 + bf1); out = h3 . Wf2 + bf2   (h2 already relu'd, bf16 planes)
__global__ void k_final(const unsigned short* __restrict__ h2_0,
                        const unsigned short* __restrict__ h2_1,
                        const float* __restrict__ Wf1, const float* __restrict__ bf1,
                        const float* __restrict__ Wf2, const float* __restrict__ bf2,
                        float* __restrict__ out, int n) {
    __shared__ float sW[1024];
    __shared__ float sh[8][33];
    int tid = threadIdx.x;
    for (int k = tid; k < 1024; k += 256) sW[k] = Wf1[k];
    int ln = tid >> 5, f = tid & 31;
    int i = blockIdx.x * 8 + ln;
    float h = 0.f;
    if (i < n) {
        const unsigned short* hp = (f < 16) ? h2_0 : h2_1;
        unsigned short u = hp[(size_t)i * 16 + (f & 15)];
        h = __uint_as_float((unsigned)u << 16);
    }
    sh[ln][f] = h;
    __syncthreads();
    float p = 0.f;
    if (i < n) {
        float a = bf1[f];
#pragma unroll
        for (int k = 0; k < 32; ++k) a += sh[ln][k] * sW[k * 32 + f];
        a = a > 0.f ? a : 0.f;
        p = a * Wf2[f];
    }
#pragma unroll
    for (int m = 16; m >= 1; m >>= 1) p += __shfl_xor(p, m, 64);
    if (f == 0 && i < n) out[i] = p + bf2[0];
}

// ---------------- launch ----------------

extern "C" void kernel_launch(void* const* d_in, const int* in_sizes, int n_in,
                              void* d_out, int out_size, void* d_ws, size_t ws_size,
                              hipStream_t stream) {
    const float* x   = (const float*)d_in[0];
    const int*   ei  = (const int*)d_in[1];
    const float* W1  = (const float*)d_in[2];
    const float* b1  = (const float*)d_in[3];
    const float* W2  = (const float*)d_in[4];
    const float* b2  = (const float*)d_in[5];
    const float* Wf1 = (const float*)d_in[6];
    const float* bf1 = (const float*)d_in[7];
    const float* Wf2 = (const float*)d_in[8];
    const float* bf2 = (const float*)d_in[9];
    float* out = (float*)d_out;

    int n = in_sizes[0] / 2;   // x is [N,2]; n=100000 (<=131072)
    int E = in_sizes[1] / 2;   // edge_index is [2,E]
    int GN = (n + NGRP - 1) / NGRP;   // 196 nodes per group

    // workspace layout, all 16B-aligned chunks (no aliasing; ws is 256MB)
    char* wp = (char*)d_ws;
    auto alloc = [&](size_t bytes) {
        char* ptr = wp;
        wp += (bytes + 15) & ~(size_t)15;
        return ptr;
    };
    int*      srclist = (int*)     alloc(sizeof(int) * (size_t)NGRP * CAP);
    unsigned* pairs   = (unsigned*)alloc(sizeof(unsigned) * (size_t)NGRP * CAP);
    int*      rowStart= (int*)     alloc(sizeof(int) * (size_t)n);
    int*      rowEnd  = (int*)     alloc(sizeof(int) * (size_t)n);
    float*    dinv    = (float*)   alloc(sizeof(float) * (size_t)n);
    float2*   z       = (float2*)  alloc(sizeof(float2) * (size_t)(n + 1));
    float2*   agg     = (float2*)  alloc(sizeof(float2) * (size_t)n);
    int*      gcursor = (int*)     alloc(sizeof(int) * NGRP);
    unsigned short* y0  = (unsigned short*)alloc(2 * (size_t)(n + 1) * 16);
    unsigned short* y1  = (unsigned short*)alloc(2 * (size_t)(n + 1) * 16);
    unsigned short* h2_0= (unsigned short*)alloc(2 * (size_t)n * 16);
    unsigned short* h2_1= (unsigned short*)alloc(2 * (size_t)n * 16);

    int nblk = (E + EPB - 1) / EPB;
    int nb = (n + 63) / 64;
    int nsg = (nb + 3) / 4;          // 8-block supergroups for plane sharding

    // CSR build — zero per-edge global atomics, single ei read, replicated LDS bins
    (void)hipMemsetAsync(gcursor, 0, NGRP * sizeof(int), stream);
    k_partition<<<nblk, PTHREADS, 0, stream>>>(ei, gcursor, pairs, E, n, GN);
    k_build<<<NGRP, 512, 0, stream>>>(gcursor, pairs, (const float2*)x, rowStart, rowEnd,
                                      srclist, dinv, z, n, GN);

    // conv1: per-lane int4-unrolled z gather, then MLP to y planes (+ zero row n)
    k_gather2f<<<(n + 255) / 256, 256, 0, stream>>>(rowStart, rowEnd, srclist, z, agg, n);
    k_mid1<<<(n + 8) / 8, 256, 0, stream>>>(agg, dinv, W1, b1, W2, y0, y1, n);

    // conv2: both planes, one launch, XCD-sharded; int4 srclist; fused h2 epilogue
    k_gather_planes<<<nsg * 8, 256, 0, stream>>>(rowStart, rowEnd, srclist,
                                                 (const uint4*)y0, (const uint4*)y1,
                                                 dinv, b2, h2_0, h2_1, n, nb);

    // MLP head from bf16 h2 planes
    k_final<<<(n + 7) / 8, 256, 0, stream>>>(h2_0, h2_1, Wf1, bf1, Wf2, bf2, out, n);
}

// Round 19
// 157.792 us; speedup vs baseline: 1.0698x; 1.0698x over previous
//
#include <hip/hip_runtime.h>

#define NGRP 512        // dst-range groups; requires n <= 131072 (SRC_BITS) and GN <= 512
#define CAP  7424       // per-group capacity incl. padding (raw ~6250+5sigma, +3*GN pad)
#define PTHREADS 1024   // partition block threads
#define NE   16         // edges per thread (4 int4 loads)
#define EPB  (PTHREADS * NE)   // 16384 edges per partition block
#define SRC_BITS 17
#define SRC_MASK 0x1FFFF

// ---- bf16 helpers (manual, RNE) ----
static __device__ __forceinline__ unsigned f2bf(float f) {
    unsigned u = __float_as_uint(f);
    return (u + 0x7FFFu + ((u >> 16) & 1u)) >> 16;
}
static __device__ __forceinline__ float bf2f_lo(unsigned u) { return __uint_as_float(u << 16); }
static __device__ __forceinline__ float bf2f_hi(unsigned u) { return __uint_as_float(u & 0xFFFF0000u); }

// ---------------- CSR build ----------------

// int4 ei reads (4 edges/instruction, per-thread consecutive-4, lane-coalesced 16B).
// gcursor[] zeroed by hipMemsetAsync; holds per-group RELATIVE counts.
__global__ __launch_bounds__(PTHREADS) void k_partition(const int* __restrict__ ei, int* gcursor,
                                                        unsigned* __restrict__ pairs,
                                                        int E, int n, int GN) {
    __shared__ int cnt[NGRP];
    __shared__ int cur[NGRP];
    int tid = threadIdx.x;
    if (tid < NGRP) cnt[tid] = 0;
    __syncthreads();
    int base = blockIdx.x * EPB;
    int sreg[NE], dreg[NE];
#pragma unroll
    for (int k4 = 0; k4 < NE / 4; ++k4) {
        int e0 = base + 4 * (tid + k4 * PTHREADS);   // 16B-aligned, lane-coalesced
        int ss[4], dd[4];
        if (e0 + 3 < E) {
            int4 sv = *(const int4*)(ei + e0);
            int4 dv = *(const int4*)(ei + E + e0);
            ss[0] = sv.x; ss[1] = sv.y; ss[2] = sv.z; ss[3] = sv.w;
            dd[0] = dv.x; dd[1] = dv.y; dd[2] = dv.z; dd[3] = dv.w;
        } else {
            for (int j = 0; j < 4; ++j) {
                int e = e0 + j;
                ss[j] = (e < E) ? ei[e] : 0;
                dd[j] = (e < E) ? ei[E + e] : -1;
            }
        }
#pragma unroll
        for (int j = 0; j < 4; ++j) {
            int s = ss[j], d = dd[j];
            if ((unsigned)s < (unsigned)n && (unsigned)d < (unsigned)n)
                atomicAdd(&cnt[d / GN], 1);
            else d = -1;
            sreg[k4 * 4 + j] = s;
            dreg[k4 * 4 + j] = d;
        }
    }
    __syncthreads();
    if (tid < NGRP) {
        int c = cnt[tid];
        int rel = c ? atomicAdd(&gcursor[tid], c) : 0;
        cur[tid] = tid * CAP + rel;           // absolute write position
    }
    __syncthreads();
#pragma unroll
    for (int k = 0; k < NE; ++k) {
        int d = dreg[k];
        if (d >= 0) {
            int g = d / GN;
            int w = atomicAdd(&cur[g], 1);
            if (w < (g + 1) * CAP)   // capacity guard: drop -> loud absmax fail, no corruption
                pairs[w] = ((unsigned)(d - g * GN) << SRC_BITS) | (unsigned)sreg[k];
        }
    }
}

// one 512-thread block per group: LDS-stage pairs, hist, PADDED scan (each node's list
// rounded to multiple of 4; pad entries -> zero-row n), rowStart/rowEnd/dinv/z, scatter.
__global__ __launch_bounds__(512) void k_build(const int* __restrict__ gcursor,
                                               const unsigned* __restrict__ pairs,
                                               const float2* __restrict__ x2,
                                               int* __restrict__ rowStart, int* __restrict__ rowEnd,
                                               int* __restrict__ srclist, float* __restrict__ dinv,
                                               float2* __restrict__ z, int n, int GN) {
    __shared__ unsigned pl[CAP];
    __shared__ int cnt[512];
    __shared__ int cur[512];
    int g = blockIdx.x;
    int t = threadIdx.x;
    int gbeg = g * CAP;
    int m = gcursor[g];                 // raw count
    const int MCAP = CAP - 600;         // leave room for padding (<= 3*GN = 588)
    if (m > MCAP) m = MCAP;             // pathological overflow -> drop (loud fail)
    cnt[t] = 0;
    if (g == 0 && t == 0) z[n] = make_float2(0.f, 0.f);   // zero row for padding
    __syncthreads();
    for (int k = t; k < m; k += 512) {
        unsigned v = pairs[gbeg + k];
        pl[k] = v;
        atomicAdd(&cnt[(v >> SRC_BITS) & 511], 1);
    }
    __syncthreads();
    int c = cnt[t];
    int rnd = (c + 3) & ~3;             // padded length (multiple of 4)
    __syncthreads();
    cnt[t] = rnd;
    __syncthreads();
    for (int off = 1; off < 512; off <<= 1) {   // inclusive scan of padded lengths
        int add = (t >= off) ? cnt[t - off] : 0;
        __syncthreads();
        cnt[t] += add;
        __syncthreads();
    }
    int excl = cnt[t] - rnd;
    int node = g * GN + t;
    int st = gbeg + excl;
    if (t < GN && node < n) {
        rowStart[node] = st;
        rowEnd[node] = st + rnd;
        float di = rsqrtf(1.0f + (float)c);
        dinv[node] = di;
        float2 xv = x2[node];
        z[node] = make_float2(xv.x * di, xv.y * di);
        for (int j = c; j < rnd; ++j) srclist[st + j] = n;   // padding -> zero row
    }
    cur[t] = excl;
    __syncthreads();
    for (int k = t; k < m; k += 512) {
        unsigned v = pl[k];
        int dl = (v >> SRC_BITS) & 511;
        int pos = atomicAdd(&cur[dl], 1);
        srclist[gbeg + pos] = (int)(v & SRC_MASK);
    }
}

// ---------------- GCN compute ----------------

// FUSED conv1: 32 lanes/node gather z cooperatively (padding hits z[n]=0), shfl-reduce,
// then h1 = relu(dinv*(agg@W1)+b1); y = bf16((h1@W2)*dinv) into two feature planes.
// Grid covers i==n to zero the y planes' padding row.
__global__ __launch_bounds__(256) void k_mid1f(const int* __restrict__ rowStart,
                                               const int* __restrict__ rowEnd,
                                               const int* __restrict__ srclist,
                                               const float2* __restrict__ z,
                                               const float* __restrict__ dinv,
                                               const float* __restrict__ W1,
                                               const float* __restrict__ b1,
                                               const float* __restrict__ W2,
                                               unsigned short* __restrict__ y0,
                                               unsigned short* __restrict__ y1, int n) {
    __shared__ float sW[1024];
    __shared__ float sh[8][33];
    int tid = threadIdx.x;
    for (int k = tid; k < 1024; k += 256) sW[k] = W2[k];
    int ln = tid >> 5, f = tid & 31;
    int i = blockIdx.x * 8 + ln;
    float ax = 0.f, ay = 0.f;
    if (i < n) {
        int e = rowStart[i] + f, end = rowEnd[i];
        for (; e < end; e += 32) {
            float2 v = z[srclist[e]];
            ax += v.x; ay += v.y;
        }
    }
#pragma unroll
    for (int m = 1; m < 32; m <<= 1) {   // stays within the node's 32-lane half
        ax += __shfl_xor(ax, m, 64);
        ay += __shfl_xor(ay, m, 64);
    }
    float h = 0.f, di = 0.f;
    if (i < n) {
        di = dinv[i];
        float2 zz = z[i];   // self-loop
        ax += zz.x; ay += zz.y;
        h = di * (ax * W1[f] + ay * W1[32 + f]) + b1[f];
        h = h > 0.f ? h : 0.f;
    }
    sh[ln][f] = h;
    __syncthreads();
    if (i < n) {
        float acc = 0.f;
#pragma unroll
        for (int k = 0; k < 32; ++k) acc += sh[ln][k] * sW[k * 32 + f];
        unsigned short* ypl = (f < 16) ? y0 : y1;
        ypl[(size_t)i * 16 + (f & 15)] = (unsigned short)f2bf(acc * di);
    } else if (i == n) {
        unsigned short* ypl = (f < 16) ? y0 : y1;   // zero row for conv2 padding
        ypl[(size_t)n * 16 + (f & 15)] = 0;
    }
}

#define ACC8(v)                                        \
    a0 += bf2f_lo((v).x); a1 += bf2f_hi((v).x);        \
    a2 += bf2f_lo((v).y); a3 += bf2f_hi((v).y);        \
    a4 += bf2f_lo((v).z); a5 += bf2f_hi((v).z);        \
    a6 += bf2f_lo((v).w); a7 += bf2f_hi((v).w);

// conv2 gather + fused epilogue: h2 = relu(dinv*sum + b2) written as bf16 planes.
// XCD-sharded planes (supergroups of 8 blocks). int4 srclist loads (rows padded to 4).
__global__ __launch_bounds__(256) void k_gather_planes(const int* __restrict__ rowStart,
                                                       const int* __restrict__ rowEnd,
                                                       const int* __restrict__ srclist,
                                                       const uint4* __restrict__ yp0,
                                                       const uint4* __restrict__ yp1,
                                                       const float* __restrict__ dinv,
                                                       const float* __restrict__ b2,
                                                       unsigned short* __restrict__ h2_0,
                                                       unsigned short* __restrict__ h2_1,
                                                       int n, int nb) {
    int blk = blockIdx.x;
    int p = (blk >> 2) & 1;                      // plane by XCD half
    int b = (blk >> 3) * 4 + (blk & 3);          // node-block index
    if (b >= nb) return;
    const uint4* yh = p ? yp1 : yp0;
    unsigned short* hp = p ? h2_1 : h2_0;
    int w = b * 64 + (threadIdx.x >> 2);
    if (w >= n) return;
    int slot = (threadIdx.x >> 1) & 1;
    int q = threadIdx.x & 1;
    int beg = rowStart[w];
    int nq = (rowEnd[w] - beg) >> 2;             // int4 quads (padding -> zero rows)
    const int4* sl4 = (const int4*)(srclist + beg);
    float a0 = 0.f, a1 = 0.f, a2 = 0.f, a3 = 0.f, a4 = 0.f, a5 = 0.f, a6 = 0.f, a7 = 0.f;
    for (int j = slot; j < nq; j += 2) {
        int4 s4 = sl4[j];
        uint4 v0 = yh[(size_t)s4.x * 2 + q];
        uint4 v1 = yh[(size_t)s4.y * 2 + q];
        uint4 v2 = yh[(size_t)s4.z * 2 + q];
        uint4 v3 = yh[(size_t)s4.w * 2 + q];
        ACC8(v0); ACC8(v1); ACC8(v2); ACC8(v3);
    }
    if (slot == 0) {                     // self-loop
        uint4 v = yh[(size_t)w * 2 + q];
        ACC8(v);
    }
    a0 += __shfl_xor(a0, 2, 64);
    a1 += __shfl_xor(a1, 2, 64);
    a2 += __shfl_xor(a2, 2, 64);
    a3 += __shfl_xor(a3, 2, 64);
    a4 += __shfl_xor(a4, 2, 64);
    a5 += __shfl_xor(a5, 2, 64);
    a6 += __shfl_xor(a6, 2, 64);
    a7 += __shfl_xor(a7, 2, 64);
    if (slot == 0) {
        float di = dinv[w];
        const float* bb = b2 + p * 16 + q * 8;
        float t0 = di * a0 + bb[0]; t0 = t0 > 0.f ? t0 : 0.f;
        float t1 = di * a1 + bb[1]; t1 = t1 > 0.f ? t1 : 0.f;
        float t2 = di * a2 + bb[2]; t2 = t2 > 0.f ? t2 : 0.f;
        float t3 = di * a3 + bb[3]; t3 = t3 > 0.f ? t3 : 0.f;
        float t4 = di * a4 + bb[4]; t4 = t4 > 0.f ? t4 : 0.f;
        float t5 = di * a5 + bb[5]; t5 = t5 > 0.f ? t5 : 0.f;
        float t6 = di * a6 + bb[6]; t6 = t6 > 0.f ? t6 : 0.f;
        float t7 = di * a7 + bb[7]; t7 = t7 > 0.f ? t7 : 0.f;
        uint4 pk;
        pk.x = f2bf(t0) | (f2bf(t1) << 16);
        pk.y = f2bf(t2) | (f2bf(t3) << 16);
        pk.z = f2bf(t4) | (f2bf(t5) << 16);
        pk.w = f2bf(t6) | (f2bf(t7) << 16);
        *(uint4*)(hp + (size_t)w * 16 + q * 8) = pk;
    }
}

// h3 = relu(h2 @ Wf1 + bf1); out = h3 . Wf2 + bf2   (h2 already relu'd, bf16 planes)
__global__ void k_final(const unsigned short* __restrict__ h2_0,
                        const unsigned short* __restrict__ h2_1,
                        const float* __restrict__ Wf1, const float* __restrict__ bf1,
                        const float* __restrict__ Wf2, const float* __restrict__ bf2,
                        float* __restrict__ out, int n) {
    __shared__ float sW[1024];
    __shared__ float sh[8][33];
    int tid = threadIdx.x;
    for (int k = tid; k < 1024; k += 256) sW[k] = Wf1[k];
    int ln = tid >> 5, f = tid & 31;
    int i = blockIdx.x * 8 + ln;
    float h = 0.f;
    if (i < n) {
        const unsigned short* hp = (f < 16) ? h2_0 : h2_1;
        unsigned short u = hp[(size_t)i * 16 + (f & 15)];
        h = __uint_as_float((unsigned)u << 16);
    }
    sh[ln][f] = h;
    __syncthreads();
    float p = 0.f;
    if (i < n) {
        float a = bf1[f];
#pragma unroll
        for (int k = 0; k < 32; ++k) a += sh[ln][k] * sW[k * 32 + f];
        a = a > 0.f ? a : 0.f;
        p = a * Wf2[f];
    }
#pragma unroll
    for (int m = 16; m >= 1; m >>= 1) p += __shfl_xor(p, m, 64);
    if (f == 0 && i < n) out[i] = p + bf2[0];
}

// ---------------- launch ----------------

extern "C" void kernel_launch(void* const* d_in, const int* in_sizes, int n_in,
                              void* d_out, int out_size, void* d_ws, size_t ws_size,
                              hipStream_t stream) {
    const float* x   = (const float*)d_in[0];
    const int*   ei  = (const int*)d_in[1];
    const float* W1  = (const float*)d_in[2];
    const float* b1  = (const float*)d_in[3];
    const float* W2  = (const float*)d_in[4];
    const float* b2  = (const float*)d_in[5];
    const float* Wf1 = (const float*)d_in[6];
    const float* bf1 = (const float*)d_in[7];
    const float* Wf2 = (const float*)d_in[8];
    const float* bf2 = (const float*)d_in[9];
    float* out = (float*)d_out;

    int n = in_sizes[0] / 2;   // x is [N,2]; n=100000 (<=131072)
    int E = in_sizes[1] / 2;   // edge_index is [2,E]
    int GN = (n + NGRP - 1) / NGRP;   // 196 nodes per group

    // workspace layout, all 16B-aligned chunks (no aliasing; ws is 256MB)
    char* wp = (char*)d_ws;
    auto alloc = [&](size_t bytes) {
        char* ptr = wp;
        wp += (bytes + 15) & ~(size_t)15;
        return ptr;
    };
    int*      srclist = (int*)     alloc(sizeof(int) * (size_t)NGRP * CAP);
    unsigned* pairs   = (unsigned*)alloc(sizeof(unsigned) * (size_t)NGRP * CAP);
    int*      rowStart= (int*)     alloc(sizeof(int) * (size_t)n);
    int*      rowEnd  = (int*)     alloc(sizeof(int) * (size_t)n);
    float*    dinv    = (float*)   alloc(sizeof(float) * (size_t)n);
    float2*   z       = (float2*)  alloc(sizeof(float2) * (size_t)(n + 1));
    int*      gcursor = (int*)     alloc(sizeof(int) * NGRP);
    unsigned short* y0  = (unsigned short*)alloc(2 * (size_t)(n + 1) * 16);
    unsigned short* y1  = (unsigned short*)alloc(2 * (size_t)(n + 1) * 16);
    unsigned short* h2_0= (unsigned short*)alloc(2 * (size_t)n * 16);
    unsigned short* h2_1= (unsigned short*)alloc(2 * (size_t)n * 16);

    int nblk = (E + EPB - 1) / EPB;
    int nb = (n + 63) / 64;
    int nsg = (nb + 3) / 4;          // 8-block supergroups for plane sharding

    // CSR build — zero per-edge global atomics, int4 ei reads
    (void)hipMemsetAsync(gcursor, 0, NGRP * sizeof(int), stream);
    k_partition<<<nblk, PTHREADS, 0, stream>>>(ei, gcursor, pairs, E, n, GN);
    k_build<<<NGRP, 512, 0, stream>>>(gcursor, pairs, (const float2*)x, rowStart, rowEnd,
                                      srclist, dinv, z, n, GN);

    // conv1 fused: cooperative z gather + MLP to y planes (+ zero row n)
    k_mid1f<<<(n + 8) / 8, 256, 0, stream>>>(rowStart, rowEnd, srclist, z, dinv,
                                             W1, b1, W2, y0, y1, n);

    // conv2: both planes, one launch, XCD-sharded; int4 srclist; fused h2 epilogue
    k_gather_planes<<<nsg * 8, 256, 0, stream>>>(rowStart, rowEnd, srclist,
                                                 (const uint4*)y0, (const uint4*)y1,
                                                 dinv, b2, h2_0, h2_1, n, nb);

    // MLP head from bf16 h2 planes
    k_final<<<(n + 7) / 8, 256, 0, stream>>>(h2_0, h2_1, Wf1, bf1, Wf2, bf2, out, n);
}